// Round 4
// baseline (523.706 us; speedup 1.0000x reference)
//
#include <hip/hip_runtime.h>
#include <stdint.h>
#include <stddef.h>

#define NB 32
#define NC 512
#define NN 4096
#define NSPLIT 4
#define KCH (NN / NSPLIT)   // 1024

typedef _Float16 h4_t __attribute__((ext_vector_type(4)));
typedef _Float16 h8_t __attribute__((ext_vector_type(8)));
typedef float    f4_t __attribute__((ext_vector_type(4)));

__device__ __forceinline__ void gload16(const _Float16* g, _Float16* l) {
    __builtin_amdgcn_global_load_lds(
        (const __attribute__((address_space(1))) void*)g,
        (__attribute__((address_space(3))) void*)l, 16, 0, 0);
}

// ---------------------------------------------------------------------------
// Pass 1a (fused path): x -> Xh, Xl, Xt in one pass. 64x64 LDS transpose.
// ---------------------------------------------------------------------------
__global__ __launch_bounds__(256) void cast_transpose(
    const float* __restrict__ x, _Float16* __restrict__ Xh,
    _Float16* __restrict__ Xl, _Float16* __restrict__ Xt)
{
    __shared__ __attribute__((aligned(16))) _Float16 tile[64 * 66];
    const int b = blockIdx.z, c0 = blockIdx.y * 64, n0 = blockIdx.x * 64;
    const int t = threadIdx.x;
    const int lr = t >> 4;          // 0..15
    const int lc = (t & 15) * 4;    // 0,4,...,60
    const size_t xbase = (size_t)b * NC * NN;

#pragma unroll
    for (int p = 0; p < 4; ++p) {
        const int r = p * 16 + lr;
        const size_t off = xbase + (size_t)(c0 + r) * NN + (n0 + lc);
        const float4 v = *(const float4*)(x + off);
        const _Float16 h0 = (_Float16)v.x, h1 = (_Float16)v.y;
        const _Float16 h2 = (_Float16)v.z, h3 = (_Float16)v.w;
        h4_t hv = {h0, h1, h2, h3};
        *(h4_t*)(Xh + off) = hv;
        h4_t lv = {(_Float16)(v.x - (float)h0), (_Float16)(v.y - (float)h1),
                   (_Float16)(v.z - (float)h2), (_Float16)(v.w - (float)h3)};
        *(h4_t*)(Xl + off) = lv;
        tile[r * 66 + lc + 0] = h0;
        tile[r * 66 + lc + 1] = h1;
        tile[r * 66 + lc + 2] = h2;
        tile[r * 66 + lc + 3] = h3;
    }
    __syncthreads();
    const size_t tbase = (size_t)b * NN * NC;
#pragma unroll
    for (int p = 0; p < 4; ++p) {
        const int rn = p * 16 + lr;
        h4_t w;
        w[0] = tile[(lc + 0) * 66 + rn];
        w[1] = tile[(lc + 1) * 66 + rn];
        w[2] = tile[(lc + 2) * 66 + rn];
        w[3] = tile[(lc + 3) * 66 + rn];
        *(h4_t*)(Xt + tbase + (size_t)(n0 + rn) * NC + (c0 + lc)) = w;
    }
}

// ---------------------------------------------------------------------------
// Pass 1b (fallback): x -> Xh, Xl only.
// ---------------------------------------------------------------------------
__global__ __launch_bounds__(256) void cast_hl(
    const float* __restrict__ x, _Float16* __restrict__ Xh,
    _Float16* __restrict__ Xl)
{
    const size_t total = (size_t)NB * NC * NN / 4;
    for (size_t i = (size_t)blockIdx.x * 256 + threadIdx.x; i < total;
         i += (size_t)gridDim.x * 256) {
        const float4 v = ((const float4*)x)[i];
        const _Float16 h0 = (_Float16)v.x, h1 = (_Float16)v.y;
        const _Float16 h2 = (_Float16)v.z, h3 = (_Float16)v.w;
        h4_t hv = {h0, h1, h2, h3};
        h4_t lv = {(_Float16)(v.x - (float)h0), (_Float16)(v.y - (float)h1),
                   (_Float16)(v.z - (float)h2), (_Float16)(v.w - (float)h3)};
        ((h4_t*)Xh)[i] = hv;
        ((h4_t*)Xl)[i] = lv;
    }
}

// ---------------------------------------------------------------------------
// Pass 2: partial energy, symmetric lower-tri tiles, split-K. m97 structure.
// LDS rows are 64 B -> XOR-swizzle (elem ^= (row&3)<<3) via pre-swizzled
// global source (rule: gload_lds dest stays linear) + swizzled frag reads.
// ---------------------------------------------------------------------------
__global__ __launch_bounds__(256, 4) void gemm1_energy(
    const _Float16* __restrict__ Xh, const _Float16* __restrict__ Xl,
    float* __restrict__ part)
{
    __shared__ __attribute__((aligned(16))) _Float16 sAh[128 * 32];
    __shared__ __attribute__((aligned(16))) _Float16 sBh[128 * 32];
    __shared__ __attribute__((aligned(16))) _Float16 sAl[128 * 32];
    __shared__ __attribute__((aligned(16))) _Float16 sBl[128 * 32];

    const int flat = blockIdx.x;          // 0..1279
    const int xcd  = flat & 7;
    const int slot = flat >> 3;           // 0..159
    const int grp  = xcd + 8 * (slot / 10);   // 0..127 (bijective)
    const int mem  = slot % 10;           // 0..9 lower-tri tile index
    const int b    = grp >> 2;
    const int s    = grp & (NSPLIT - 1);

    const int ti = (int)((sqrtf(8.0f * (float)mem + 1.0f) - 1.0f) * 0.5f);
    const int tj = mem - ((ti * (ti + 1)) >> 1);
    const bool diag = (ti == tj);

    const int t = threadIdx.x;
    const int wave = t >> 6, lane = t & 63;
    const int srow = t >> 2;
    // pre-swizzled staging column: logical chunk = phys ^ (row&3)
    const int scol = (((t & 3) ^ ((t >> 2) & 3)) * 8);

    const size_t xb = (size_t)b * NC * NN + (size_t)s * KCH;
    const _Float16* gAh = Xh + xb + (size_t)(ti * 128 + srow) * NN + scol;
    const _Float16* gBh = Xh + xb + (size_t)(tj * 128 + srow) * NN + scol;
    const _Float16* gAl = Xl + xb + (size_t)(ti * 128 + srow) * NN + scol;
    const _Float16* gBl = Xl + xb + (size_t)(tj * 128 + srow) * NN + scol;

    const int wr = wave >> 1, wc = wave & 1;
    const int fr = lane & 15, fko = (lane >> 4) * 8;
    const int hi4 = (lane >> 4) * 4;
    const int fsw = fko ^ ((fr & 3) << 3);   // swizzled k-offset (row&3 == fr&3)

    const _Float16* rBh = diag ? sAh : sBh;
    const _Float16* rBl = diag ? sAl : sBl;

    f4_t acc[4][4];
#pragma unroll
    for (int m = 0; m < 4; ++m)
#pragma unroll
        for (int n = 0; n < 4; ++n) acc[m][n] = (f4_t){0.f, 0.f, 0.f, 0.f};

    for (int k0 = 0; k0 < KCH; k0 += 32) {
        gload16(gAh + k0,                   sAh + wave * 512);
        gload16(gAh + k0 + 64 * (size_t)NN, sAh + 2048 + wave * 512);
        gload16(gAl + k0,                   sAl + wave * 512);
        gload16(gAl + k0 + 64 * (size_t)NN, sAl + 2048 + wave * 512);
        if (!diag) {
            gload16(gBh + k0,                   sBh + wave * 512);
            gload16(gBh + k0 + 64 * (size_t)NN, sBh + 2048 + wave * 512);
            gload16(gBl + k0,                   sBl + wave * 512);
            gload16(gBl + k0 + 64 * (size_t)NN, sBl + 2048 + wave * 512);
        }
        __syncthreads();

        h8_t ah[4], bh[4], al[4], bl[4];
#pragma unroll
        for (int m = 0; m < 4; ++m) {
            ah[m] = *(const h8_t*)(sAh + (wr * 64 + m * 16 + fr) * 32 + fsw);
            bh[m] = *(const h8_t*)(rBh + (wc * 64 + m * 16 + fr) * 32 + fsw);
            al[m] = *(const h8_t*)(sAl + (wr * 64 + m * 16 + fr) * 32 + fsw);
            bl[m] = *(const h8_t*)(rBl + (wc * 64 + m * 16 + fr) * 32 + fsw);
        }
#pragma unroll
        for (int m = 0; m < 4; ++m)
#pragma unroll
            for (int nf = 0; nf < 4; ++nf) {
                acc[nf][m] = __builtin_amdgcn_mfma_f32_16x16x32_f16(bh[nf], ah[m], acc[nf][m], 0, 0, 0);
                acc[nf][m] = __builtin_amdgcn_mfma_f32_16x16x32_f16(bl[nf], ah[m], acc[nf][m], 0, 0, 0);
                acc[nf][m] = __builtin_amdgcn_mfma_f32_16x16x32_f16(bh[nf], al[m], acc[nf][m], 0, 0, 0);
            }
        __syncthreads();
    }

    float* pb = part + ((size_t)s * NB + b) * (NC * NC);
#pragma unroll
    for (int m = 0; m < 4; ++m) {
        const int i = ti * 128 + wr * 64 + m * 16 + fr;
#pragma unroll
        for (int nf = 0; nf < 4; ++nf) {
            const int jjb = tj * 128 + wc * 64 + nf * 16 + hi4;
            *(f4_t*)(pb + (size_t)i * NC + jjb) = acc[nf][m];
            if (!diag) {
#pragma unroll
                for (int j = 0; j < 4; ++j)
                    pb[(size_t)(jjb + j) * NC + i] = acc[nf][m][j];
            }
        }
    }
}

// ---------------------------------------------------------------------------
// Pass 3: attn = softmax(min(e) - e), e = sum of NSPLIT partials. 1 wave/row.
// ---------------------------------------------------------------------------
__global__ __launch_bounds__(256) void softmax_inv(
    const float* __restrict__ part, _Float16* __restrict__ attn)
{
    const int row = blockIdx.x * 4 + (threadIdx.x >> 6);
    const int lane = threadIdx.x & 63;
    const size_t roff = (size_t)row * NC;

    float4 a0 = {0.f, 0.f, 0.f, 0.f}, a1 = {0.f, 0.f, 0.f, 0.f};
#pragma unroll
    for (int s = 0; s < NSPLIT; ++s) {
        const float4* p = (const float4*)(part + (size_t)s * NB * NC * NC + roff);
        const float4 v0 = p[lane], v1 = p[64 + lane];
        a0.x += v0.x; a0.y += v0.y; a0.z += v0.z; a0.w += v0.w;
        a1.x += v1.x; a1.y += v1.y; a1.z += v1.z; a1.w += v1.w;
    }

    float mn = fminf(fminf(fminf(a0.x, a0.y), fminf(a0.z, a0.w)),
                     fminf(fminf(a1.x, a1.y), fminf(a1.z, a1.w)));
#pragma unroll
    for (int off = 32; off; off >>= 1) mn = fminf(mn, __shfl_xor(mn, off));

    const float w0 = __expf(mn - a0.x), w1 = __expf(mn - a0.y);
    const float w2 = __expf(mn - a0.z), w3 = __expf(mn - a0.w);
    const float w4 = __expf(mn - a1.x), w5 = __expf(mn - a1.y);
    const float w6 = __expf(mn - a1.z), w7 = __expf(mn - a1.w);
    float sum = ((w0 + w1) + (w2 + w3)) + ((w4 + w5) + (w6 + w7));
#pragma unroll
    for (int off = 32; off; off >>= 1) sum += __shfl_xor(sum, off);
    const float inv = 1.0f / sum;

    h4_t o0 = {(_Float16)(w0 * inv), (_Float16)(w1 * inv),
               (_Float16)(w2 * inv), (_Float16)(w3 * inv)};
    h4_t o1 = {(_Float16)(w4 * inv), (_Float16)(w5 * inv),
               (_Float16)(w6 * inv), (_Float16)(w7 * inv)};
    ((h4_t*)(attn + roff))[lane] = o0;
    ((h4_t*)(attn + roff))[64 + lane] = o1;
}

// ---------------------------------------------------------------------------
// Pass 4 (fallback only): Xt = Xh^T per batch.
// ---------------------------------------------------------------------------
__global__ __launch_bounds__(256) void transpose_h(
    const _Float16* __restrict__ Xh, _Float16* __restrict__ Xt)
{
    __shared__ __attribute__((aligned(16))) _Float16 tile[64 * 66];
    const int b = blockIdx.z, c0 = blockIdx.y * 64, n0 = blockIdx.x * 64;
    const int t = threadIdx.x;
    const int lr = t >> 4;
    const int lc = (t & 15) * 4;
    const size_t hbase = (size_t)b * NC * NN;

#pragma unroll
    for (int p = 0; p < 4; ++p) {
        const int r = p * 16 + lr;
        const h4_t v = *(const h4_t*)(Xh + hbase + (size_t)(c0 + r) * NN + (n0 + lc));
        tile[r * 66 + lc + 0] = v[0];
        tile[r * 66 + lc + 1] = v[1];
        tile[r * 66 + lc + 2] = v[2];
        tile[r * 66 + lc + 3] = v[3];
    }
    __syncthreads();
    const size_t tbase = (size_t)b * NN * NC;
#pragma unroll
    for (int p = 0; p < 4; ++p) {
        const int rn = p * 16 + lr;
        h4_t w;
        w[0] = tile[(lc + 0) * 66 + rn];
        w[1] = tile[(lc + 1) * 66 + rn];
        w[2] = tile[(lc + 2) * 66 + rn];
        w[3] = tile[(lc + 3) * 66 + rn];
        *(h4_t*)(Xt + tbase + (size_t)(n0 + rn) * NC + (c0 + lc)) = w;
    }
}

// ---------------------------------------------------------------------------
// Pass 5: out = gamma * (attn @ x) + x.
// BK=64, double-buffered B (Xt) with one barrier/iter; attn (A) fragments
// read directly from global (L2-resident, batch pinned to XCD).
// B tile rows are 128 B -> XOR-swizzle ((row&7)<<3) with pre-swizzled source.
// ---------------------------------------------------------------------------
__global__ __launch_bounds__(256) void gemm2_out(
    const _Float16* __restrict__ attn, const _Float16* __restrict__ Xt,
    const _Float16* __restrict__ Xh, const float* __restrict__ gammap,
    float* __restrict__ out)
{
    __shared__ __attribute__((aligned(16))) _Float16 sB[2][128 * 64];

    const int flat = blockIdx.x;            // 0..4095
    const int xcd  = flat & 7;
    const int slot = flat >> 3;              // 0..511
    const int b    = xcd + 8 * (slot >> 7);  // batch pinned to XCD
    const int memb = slot & 127;
    const int brow = (memb & 3) * 128;       // c tile (4)
    const int bcol = (memb >> 2) * 128;      // n tile (32)

    const int t = threadIdx.x;
    const int wave = t >> 6, lane = t & 63;
    const int wr = wave >> 1, wc = wave & 1;
    const int fr = lane & 15, fko = (lane >> 4) * 8;
    const int hi4 = (lane >> 4) * 4;
    const int bsw = (fr & 7) << 3;           // B-read swizzle (row&7 == fr&7)

    // staging: thread t covers row rr=t>>3 (of 32-row pass), phys chunk t&7;
    // pre-swizzled source chunk = (t&7) ^ (row&7)
    const int rr = t >> 3;
    const int sck = (((t & 7) ^ (rr & 7)) * 8);
    const _Float16* gB = Xt + (size_t)b * NN * NC + (size_t)bcol * NC;
    const _Float16* gA = attn + (size_t)b * NC * NC;

    f4_t acc[4][4];
#pragma unroll
    for (int m = 0; m < 4; ++m)
#pragma unroll
        for (int n = 0; n < 4; ++n) acc[m][n] = (f4_t){0.f, 0.f, 0.f, 0.f};

#define STAGE_B(buf, k0)                                                     \
    {                                                                        \
        _Pragma("unroll")                                                    \
        for (int p = 0; p < 4; ++p)                                          \
            gload16(gB + (size_t)(p * 32 + rr) * NC + (k0) + sck,            \
                    &sB[buf][0] + p * 2048 + wave * 512 + (lane)*8);         \
    }

    STAGE_B(0, 0);
    __syncthreads();

    int cur = 0;
#pragma unroll
    for (int it = 0; it < 8; ++it) {
        const int k0 = it * 64;
        if (it < 7) STAGE_B(cur ^ 1, k0 + 64);

        // A fragments direct from global (attn slab is L2-resident)
        h8_t a_[4][2];
#pragma unroll
        for (int m = 0; m < 4; ++m) {
            const size_t ar = (size_t)(brow + wr * 64 + m * 16 + fr) * NC + k0;
            a_[m][0] = *(const h8_t*)(gA + ar + fko);
            a_[m][1] = *(const h8_t*)(gA + ar + 32 + fko);
        }
#pragma unroll
        for (int kk = 0; kk < 2; ++kk) {
            h8_t b_[4];
#pragma unroll
            for (int nf = 0; nf < 4; ++nf) {
                const int row = wc * 64 + nf * 16 + fr;
                b_[nf] = *(const h8_t*)(&sB[cur][0] + row * 64 +
                                        ((kk * 32 + fko) ^ bsw));
            }
#pragma unroll
            for (int m = 0; m < 4; ++m)
#pragma unroll
                for (int nf = 0; nf < 4; ++nf)
                    acc[nf][m] = __builtin_amdgcn_mfma_f32_16x16x32_f16(
                        b_[nf], a_[m][kk], acc[nf][m], 0, 0, 0);
        }
        __syncthreads();
        cur ^= 1;
    }
#undef STAGE_B

    const float g = gammap[0];
    const _Float16* xb = Xh + (size_t)b * NC * NN;
    float* ob = out + (size_t)b * NC * NN;
#pragma unroll
    for (int m = 0; m < 4; ++m) {
        const int c_ = brow + wr * 64 + m * 16 + fr;
#pragma unroll
        for (int nf = 0; nf < 4; ++nf) {
            const int n_ = bcol + wc * 64 + nf * 16 + hi4;
            const size_t off = (size_t)c_ * NN + n_;
            const h4_t xv = *(const h4_t*)(xb + off);
            f4_t o;
#pragma unroll
            for (int j = 0; j < 4; ++j)
                o[j] = g * acc[nf][m][j] + (float)xv[j];
            *(f4_t*)(ob + off) = o;
        }
    }
}

// ---------------------------------------------------------------------------
extern "C" void kernel_launch(void* const* d_in, const int* in_sizes, int n_in,
                              void* d_out, int out_size, void* d_ws, size_t ws_size,
                              hipStream_t stream)
{
    const float* x     = (const float*)d_in[0];
    const float* gamma = (const float*)d_in[1];
    float* out = (float*)d_out;
    char* ws = (char*)d_ws;

    if (ws_size >= 553648128ull) {
        // Fused path: Xh | Xl | Xt | attn | part
        _Float16* Xh   = (_Float16*)(ws);
        _Float16* Xl   = (_Float16*)(ws + 134217728ull);
        _Float16* Xt   = (_Float16*)(ws + 268435456ull);
        _Float16* attn = (_Float16*)(ws + 402653184ull);
        float*    part = (float*)   (ws + 419430400ull);

        cast_transpose<<<dim3(NN / 64, NC / 64, NB), 256, 0, stream>>>(x, Xh, Xl, Xt);
        gemm1_energy<<<dim3(10 * NSPLIT * NB), 256, 0, stream>>>(Xh, Xl, part);
        softmax_inv<<<dim3(NB * NC / 4), 256, 0, stream>>>(part, attn);
        gemm2_out<<<dim3(4096), 256, 0, stream>>>(attn, Xt, Xh, gamma, out);
    } else {
        // Fallback: Xh | Xl/Xt (time-shared) | attn | part
        _Float16* Xh   = (_Float16*)(ws);
        _Float16* XlXt = (_Float16*)(ws + 134217728ull);
        _Float16* attn = (_Float16*)(ws + 268435456ull);
        float*    part = (float*)   (ws + 285212672ull);

        cast_hl<<<dim3(2048), 256, 0, stream>>>(x, Xh, XlXt);
        gemm1_energy<<<dim3(10 * NSPLIT * NB), 256, 0, stream>>>(Xh, XlXt, part);
        softmax_inv<<<dim3(NB * NC / 4), 256, 0, stream>>>(part, attn);
        transpose_h<<<dim3(NN / 64, NC / 64, NB), 256, 0, stream>>>(Xh, XlXt);
        gemm2_out<<<dim3(4096), 256, 0, stream>>>(attn, XlXt, Xh, gamma, out);
    }
}

// Round 5
// 476.648 us; speedup vs baseline: 1.0987x; 1.0987x over previous
//
#include <hip/hip_runtime.h>
#include <stdint.h>
#include <stddef.h>

#define NB 32
#define NC 512
#define NN 4096
#define NSPLIT 4
#define KCH (NN / NSPLIT)   // 1024

typedef _Float16 h4_t __attribute__((ext_vector_type(4)));
typedef _Float16 h8_t __attribute__((ext_vector_type(8)));
typedef float    f4_t __attribute__((ext_vector_type(4)));

__device__ __forceinline__ void gload16(const _Float16* g, _Float16* l) {
    __builtin_amdgcn_global_load_lds(
        (const __attribute__((address_space(1))) void*)g,
        (__attribute__((address_space(3))) void*)l, 16, 0, 0);
}

// Swizzle convention for [rows][32 k] fp16 LDS tiles (64 B rows, bank period
// = 2 rows): logical k-chunk q (8 elems) of row r lives at phys chunk
// q ^ ((r>>1)&3).  Staged via pre-swizzled global source (gload_lds dest
// stays linear), read back with the same XOR.

// ---------------------------------------------------------------------------
// Pass 1a (fused path): x -> Xh, Xl, Xt in one pass. 64x64 LDS transpose.
// ---------------------------------------------------------------------------
__global__ __launch_bounds__(256) void cast_transpose(
    const float* __restrict__ x, _Float16* __restrict__ Xh,
    _Float16* __restrict__ Xl, _Float16* __restrict__ Xt)
{
    __shared__ __attribute__((aligned(16))) _Float16 tile[64 * 66];
    const int b = blockIdx.z, c0 = blockIdx.y * 64, n0 = blockIdx.x * 64;
    const int t = threadIdx.x;
    const int lr = t >> 4;          // 0..15
    const int lc = (t & 15) * 4;    // 0,4,...,60
    const size_t xbase = (size_t)b * NC * NN;

#pragma unroll
    for (int p = 0; p < 4; ++p) {
        const int r = p * 16 + lr;
        const size_t off = xbase + (size_t)(c0 + r) * NN + (n0 + lc);
        const float4 v = *(const float4*)(x + off);
        const _Float16 h0 = (_Float16)v.x, h1 = (_Float16)v.y;
        const _Float16 h2 = (_Float16)v.z, h3 = (_Float16)v.w;
        h4_t hv = {h0, h1, h2, h3};
        *(h4_t*)(Xh + off) = hv;
        h4_t lv = {(_Float16)(v.x - (float)h0), (_Float16)(v.y - (float)h1),
                   (_Float16)(v.z - (float)h2), (_Float16)(v.w - (float)h3)};
        *(h4_t*)(Xl + off) = lv;
        tile[r * 66 + lc + 0] = h0;
        tile[r * 66 + lc + 1] = h1;
        tile[r * 66 + lc + 2] = h2;
        tile[r * 66 + lc + 3] = h3;
    }
    __syncthreads();
    const size_t tbase = (size_t)b * NN * NC;
#pragma unroll
    for (int p = 0; p < 4; ++p) {
        const int rn = p * 16 + lr;
        h4_t w;
        w[0] = tile[(lc + 0) * 66 + rn];
        w[1] = tile[(lc + 1) * 66 + rn];
        w[2] = tile[(lc + 2) * 66 + rn];
        w[3] = tile[(lc + 3) * 66 + rn];
        *(h4_t*)(Xt + tbase + (size_t)(n0 + rn) * NC + (c0 + lc)) = w;
    }
}

// ---------------------------------------------------------------------------
// Pass 1b (fallback): x -> Xh, Xl only.
// ---------------------------------------------------------------------------
__global__ __launch_bounds__(256) void cast_hl(
    const float* __restrict__ x, _Float16* __restrict__ Xh,
    _Float16* __restrict__ Xl)
{
    const size_t total = (size_t)NB * NC * NN / 4;
    for (size_t i = (size_t)blockIdx.x * 256 + threadIdx.x; i < total;
         i += (size_t)gridDim.x * 256) {
        const float4 v = ((const float4*)x)[i];
        const _Float16 h0 = (_Float16)v.x, h1 = (_Float16)v.y;
        const _Float16 h2 = (_Float16)v.z, h3 = (_Float16)v.w;
        h4_t hv = {h0, h1, h2, h3};
        h4_t lv = {(_Float16)(v.x - (float)h0), (_Float16)(v.y - (float)h1),
                   (_Float16)(v.z - (float)h2), (_Float16)(v.w - (float)h3)};
        ((h4_t*)Xh)[i] = hv;
        ((h4_t*)Xl)[i] = lv;
    }
}

// ---------------------------------------------------------------------------
// Pass 2: partial energy, symmetric lower-tri tiles, split-K. m97 structure.
// Corrected LDS swizzle: chunk ^= (row>>1)&3  (2-way = free).
// ---------------------------------------------------------------------------
__global__ __launch_bounds__(256, 4) void gemm1_energy(
    const _Float16* __restrict__ Xh, const _Float16* __restrict__ Xl,
    float* __restrict__ part)
{
    __shared__ __attribute__((aligned(16))) _Float16 sAh[128 * 32];
    __shared__ __attribute__((aligned(16))) _Float16 sBh[128 * 32];
    __shared__ __attribute__((aligned(16))) _Float16 sAl[128 * 32];
    __shared__ __attribute__((aligned(16))) _Float16 sBl[128 * 32];

    const int flat = blockIdx.x;          // 0..1279
    const int xcd  = flat & 7;
    const int slot = flat >> 3;           // 0..159
    const int grp  = xcd + 8 * (slot / 10);   // 0..127 (bijective)
    const int mem  = slot % 10;           // 0..9 lower-tri tile index
    const int b    = grp >> 2;
    const int s    = grp & (NSPLIT - 1);

    const int ti = (int)((sqrtf(8.0f * (float)mem + 1.0f) - 1.0f) * 0.5f);
    const int tj = mem - ((ti * (ti + 1)) >> 1);
    const bool diag = (ti == tj);

    const int t = threadIdx.x;
    const int wave = t >> 6, lane = t & 63;
    const int srow = t >> 2;
    // pre-swizzled staging source: logical chunk = phys ^ ((row>>1)&3)
    const int scol = (((t & 3) ^ ((t >> 3) & 3)) * 8);

    const size_t xb = (size_t)b * NC * NN + (size_t)s * KCH;
    const _Float16* gAh = Xh + xb + (size_t)(ti * 128 + srow) * NN + scol;
    const _Float16* gBh = Xh + xb + (size_t)(tj * 128 + srow) * NN + scol;
    const _Float16* gAl = Xl + xb + (size_t)(ti * 128 + srow) * NN + scol;
    const _Float16* gBl = Xl + xb + (size_t)(tj * 128 + srow) * NN + scol;

    const int wr = wave >> 1, wc = wave & 1;
    const int fr = lane & 15, fko = (lane >> 4) * 8;
    const int hi4 = (lane >> 4) * 4;
    const int fsw = fko ^ (((fr >> 1) & 3) << 3);   // read swizzle

    const _Float16* rBh = diag ? sAh : sBh;
    const _Float16* rBl = diag ? sAl : sBl;

    f4_t acc[4][4];
#pragma unroll
    for (int m = 0; m < 4; ++m)
#pragma unroll
        for (int n = 0; n < 4; ++n) acc[m][n] = (f4_t){0.f, 0.f, 0.f, 0.f};

    for (int k0 = 0; k0 < KCH; k0 += 32) {
        gload16(gAh + k0,                   sAh + wave * 512);
        gload16(gAh + k0 + 64 * (size_t)NN, sAh + 2048 + wave * 512);
        gload16(gAl + k0,                   sAl + wave * 512);
        gload16(gAl + k0 + 64 * (size_t)NN, sAl + 2048 + wave * 512);
        if (!diag) {
            gload16(gBh + k0,                   sBh + wave * 512);
            gload16(gBh + k0 + 64 * (size_t)NN, sBh + 2048 + wave * 512);
            gload16(gBl + k0,                   sBl + wave * 512);
            gload16(gBl + k0 + 64 * (size_t)NN, sBl + 2048 + wave * 512);
        }
        __syncthreads();

        h8_t ah[4], bh[4], al[4], bl[4];
#pragma unroll
        for (int m = 0; m < 4; ++m) {
            ah[m] = *(const h8_t*)(sAh + (wr * 64 + m * 16 + fr) * 32 + fsw);
            bh[m] = *(const h8_t*)(rBh + (wc * 64 + m * 16 + fr) * 32 + fsw);
            al[m] = *(const h8_t*)(sAl + (wr * 64 + m * 16 + fr) * 32 + fsw);
            bl[m] = *(const h8_t*)(rBl + (wc * 64 + m * 16 + fr) * 32 + fsw);
        }
#pragma unroll
        for (int m = 0; m < 4; ++m)
#pragma unroll
            for (int nf = 0; nf < 4; ++nf) {
                acc[nf][m] = __builtin_amdgcn_mfma_f32_16x16x32_f16(bh[nf], ah[m], acc[nf][m], 0, 0, 0);
                acc[nf][m] = __builtin_amdgcn_mfma_f32_16x16x32_f16(bl[nf], ah[m], acc[nf][m], 0, 0, 0);
                acc[nf][m] = __builtin_amdgcn_mfma_f32_16x16x32_f16(bh[nf], al[m], acc[nf][m], 0, 0, 0);
            }
        __syncthreads();
    }

    float* pb = part + ((size_t)s * NB + b) * (NC * NC);
#pragma unroll
    for (int m = 0; m < 4; ++m) {
        const int i = ti * 128 + wr * 64 + m * 16 + fr;
#pragma unroll
        for (int nf = 0; nf < 4; ++nf) {
            const int jjb = tj * 128 + wc * 64 + nf * 16 + hi4;
            *(f4_t*)(pb + (size_t)i * NC + jjb) = acc[nf][m];
            if (!diag) {
#pragma unroll
                for (int j = 0; j < 4; ++j)
                    pb[(size_t)(jjb + j) * NC + i] = acc[nf][m][j];
            }
        }
    }
}

// ---------------------------------------------------------------------------
// Pass 3: attn = softmax(min(e) - e), e = sum of NSPLIT partials. 1 wave/row.
// ---------------------------------------------------------------------------
__global__ __launch_bounds__(256) void softmax_inv(
    const float* __restrict__ part, _Float16* __restrict__ attn)
{
    const int row = blockIdx.x * 4 + (threadIdx.x >> 6);
    const int lane = threadIdx.x & 63;
    const size_t roff = (size_t)row * NC;

    float4 a0 = {0.f, 0.f, 0.f, 0.f}, a1 = {0.f, 0.f, 0.f, 0.f};
#pragma unroll
    for (int s = 0; s < NSPLIT; ++s) {
        const float4* p = (const float4*)(part + (size_t)s * NB * NC * NC + roff);
        const float4 v0 = p[lane], v1 = p[64 + lane];
        a0.x += v0.x; a0.y += v0.y; a0.z += v0.z; a0.w += v0.w;
        a1.x += v1.x; a1.y += v1.y; a1.z += v1.z; a1.w += v1.w;
    }

    float mn = fminf(fminf(fminf(a0.x, a0.y), fminf(a0.z, a0.w)),
                     fminf(fminf(a1.x, a1.y), fminf(a1.z, a1.w)));
#pragma unroll
    for (int off = 32; off; off >>= 1) mn = fminf(mn, __shfl_xor(mn, off));

    const float w0 = __expf(mn - a0.x), w1 = __expf(mn - a0.y);
    const float w2 = __expf(mn - a0.z), w3 = __expf(mn - a0.w);
    const float w4 = __expf(mn - a1.x), w5 = __expf(mn - a1.y);
    const float w6 = __expf(mn - a1.z), w7 = __expf(mn - a1.w);
    float sum = ((w0 + w1) + (w2 + w3)) + ((w4 + w5) + (w6 + w7));
#pragma unroll
    for (int off = 32; off; off >>= 1) sum += __shfl_xor(sum, off);
    const float inv = 1.0f / sum;

    h4_t o0 = {(_Float16)(w0 * inv), (_Float16)(w1 * inv),
               (_Float16)(w2 * inv), (_Float16)(w3 * inv)};
    h4_t o1 = {(_Float16)(w4 * inv), (_Float16)(w5 * inv),
               (_Float16)(w6 * inv), (_Float16)(w7 * inv)};
    ((h4_t*)(attn + roff))[lane] = o0;
    ((h4_t*)(attn + roff))[64 + lane] = o1;
}

// ---------------------------------------------------------------------------
// Pass 4 (fallback only): Xt = Xh^T per batch.
// ---------------------------------------------------------------------------
__global__ __launch_bounds__(256) void transpose_h(
    const _Float16* __restrict__ Xh, _Float16* __restrict__ Xt)
{
    __shared__ __attribute__((aligned(16))) _Float16 tile[64 * 66];
    const int b = blockIdx.z, c0 = blockIdx.y * 64, n0 = blockIdx.x * 64;
    const int t = threadIdx.x;
    const int lr = t >> 4;
    const int lc = (t & 15) * 4;
    const size_t hbase = (size_t)b * NC * NN;

#pragma unroll
    for (int p = 0; p < 4; ++p) {
        const int r = p * 16 + lr;
        const h4_t v = *(const h4_t*)(Xh + hbase + (size_t)(c0 + r) * NN + (n0 + lc));
        tile[r * 66 + lc + 0] = v[0];
        tile[r * 66 + lc + 1] = v[1];
        tile[r * 66 + lc + 2] = v[2];
        tile[r * 66 + lc + 3] = v[3];
    }
    __syncthreads();
    const size_t tbase = (size_t)b * NN * NC;
#pragma unroll
    for (int p = 0; p < 4; ++p) {
        const int rn = p * 16 + lr;
        h4_t w;
        w[0] = tile[(lc + 0) * 66 + rn];
        w[1] = tile[(lc + 1) * 66 + rn];
        w[2] = tile[(lc + 2) * 66 + rn];
        w[3] = tile[(lc + 3) * 66 + rn];
        *(h4_t*)(Xt + tbase + (size_t)(n0 + rn) * NC + (c0 + lc)) = w;
    }
}

// ---------------------------------------------------------------------------
// Pass 5: out = gamma * (attn @ x) + x.  R3 structure (2-barrier, BK=32,
// LDS A+B, 16 KB) + corrected read swizzle on both operands.
// ---------------------------------------------------------------------------
__global__ __launch_bounds__(256) void gemm2_out(
    const _Float16* __restrict__ attn, const _Float16* __restrict__ Xt,
    const _Float16* __restrict__ Xh, const float* __restrict__ gammap,
    float* __restrict__ out)
{
    __shared__ __attribute__((aligned(16))) _Float16 sA[128 * 32];
    __shared__ __attribute__((aligned(16))) _Float16 sB[128 * 32];

    const int flat = blockIdx.x;            // 0..4095
    const int xcd  = flat & 7;
    const int slot = flat >> 3;              // 0..511
    const int b    = xcd + 8 * (slot >> 7);  // batch pinned to XCD
    const int memb = slot & 127;
    const int brow = (memb & 3) * 128;       // c tile (4)
    const int bcol = (memb >> 2) * 128;      // n tile (32)

    const int t = threadIdx.x;
    const int wave = t >> 6, lane = t & 63;
    const int srow = t >> 2;
    const int scol = (((t & 3) ^ ((t >> 3) & 3)) * 8);   // pre-swizzled source

    const _Float16* gA = attn + (size_t)b * NC * NC + (size_t)(brow + srow) * NC + scol;
    const _Float16* gB = Xt   + (size_t)b * NN * NC + (size_t)(bcol + srow) * NC + scol;

    const int wr = wave >> 1, wc = wave & 1;
    const int fr = lane & 15, fko = (lane >> 4) * 8;
    const int hi4 = (lane >> 4) * 4;
    const int fsw = fko ^ (((fr >> 1) & 3) << 3);        // read swizzle

    f4_t acc[4][4];
#pragma unroll
    for (int m = 0; m < 4; ++m)
#pragma unroll
        for (int n = 0; n < 4; ++n) acc[m][n] = (f4_t){0.f, 0.f, 0.f, 0.f};

    for (int k0 = 0; k0 < NC; k0 += 32) {
        gload16(gA + k0,           sA + wave * 512);
        gload16(gA + k0 + 64 * NC, sA + 2048 + wave * 512);
        gload16(gB + k0,           sB + wave * 512);
        gload16(gB + k0 + 64 * NC, sB + 2048 + wave * 512);
        __syncthreads();

        h8_t a[4], bb[4];
#pragma unroll
        for (int m = 0; m < 4; ++m) {
            a[m]  = *(const h8_t*)(sA + (wr * 64 + m * 16 + fr) * 32 + fsw);
            bb[m] = *(const h8_t*)(sB + (wc * 64 + m * 16 + fr) * 32 + fsw);
        }
#pragma unroll
        for (int m = 0; m < 4; ++m)
#pragma unroll
            for (int nf = 0; nf < 4; ++nf)
                acc[nf][m] = __builtin_amdgcn_mfma_f32_16x16x32_f16(bb[nf], a[m], acc[nf][m], 0, 0, 0);
        __syncthreads();
    }

    const float g = gammap[0];
    const _Float16* xb = Xh + (size_t)b * NC * NN;
    float* ob = out + (size_t)b * NC * NN;
#pragma unroll
    for (int m = 0; m < 4; ++m) {
        const int c_ = brow + wr * 64 + m * 16 + fr;
#pragma unroll
        for (int nf = 0; nf < 4; ++nf) {
            const int n_ = bcol + wc * 64 + nf * 16 + hi4;
            const size_t off = (size_t)c_ * NN + n_;
            const h4_t xv = *(const h4_t*)(xb + off);
            f4_t o;
#pragma unroll
            for (int j = 0; j < 4; ++j)
                o[j] = g * acc[nf][m][j] + (float)xv[j];
            *(f4_t*)(ob + off) = o;
        }
    }
}

// ---------------------------------------------------------------------------
extern "C" void kernel_launch(void* const* d_in, const int* in_sizes, int n_in,
                              void* d_out, int out_size, void* d_ws, size_t ws_size,
                              hipStream_t stream)
{
    const float* x     = (const float*)d_in[0];
    const float* gamma = (const float*)d_in[1];
    float* out = (float*)d_out;
    char* ws = (char*)d_ws;

    if (ws_size >= 553648128ull) {
        // Fused path: Xh | Xl | Xt | attn | part
        _Float16* Xh   = (_Float16*)(ws);
        _Float16* Xl   = (_Float16*)(ws + 134217728ull);
        _Float16* Xt   = (_Float16*)(ws + 268435456ull);
        _Float16* attn = (_Float16*)(ws + 402653184ull);
        float*    part = (float*)   (ws + 419430400ull);

        cast_transpose<<<dim3(NN / 64, NC / 64, NB), 256, 0, stream>>>(x, Xh, Xl, Xt);
        gemm1_energy<<<dim3(10 * NSPLIT * NB), 256, 0, stream>>>(Xh, Xl, part);
        softmax_inv<<<dim3(NB * NC / 4), 256, 0, stream>>>(part, attn);
        gemm2_out<<<dim3(4096), 256, 0, stream>>>(attn, Xt, Xh, gamma, out);
    } else {
        // Fallback: Xh | Xl/Xt (time-shared) | attn | part
        _Float16* Xh   = (_Float16*)(ws);
        _Float16* XlXt = (_Float16*)(ws + 134217728ull);
        _Float16* attn = (_Float16*)(ws + 268435456ull);
        float*    part = (float*)   (ws + 285212672ull);

        cast_hl<<<dim3(2048), 256, 0, stream>>>(x, Xh, XlXt);
        gemm1_energy<<<dim3(10 * NSPLIT * NB), 256, 0, stream>>>(Xh, XlXt, part);
        softmax_inv<<<dim3(NB * NC / 4), 256, 0, stream>>>(part, attn);
        transpose_h<<<dim3(NN / 64, NC / 64, NB), 256, 0, stream>>>(Xh, XlXt);
        gemm2_out<<<dim3(4096), 256, 0, stream>>>(attn, XlXt, Xh, gamma, out);
    }
}

// Round 6
// 465.258 us; speedup vs baseline: 1.1256x; 1.0245x over previous
//
#include <hip/hip_runtime.h>
#include <stdint.h>
#include <stddef.h>

#define NB 32
#define NC 512
#define NN 4096
#define NSPLIT 4
#define KCH (NN / NSPLIT)   // 1024

typedef _Float16 h4_t __attribute__((ext_vector_type(4)));
typedef _Float16 h8_t __attribute__((ext_vector_type(8)));
typedef float    f4_t __attribute__((ext_vector_type(4)));

__device__ __forceinline__ void gload16(const _Float16* g, _Float16* l) {
    __builtin_amdgcn_global_load_lds(
        (const __attribute__((address_space(1))) void*)g,
        (__attribute__((address_space(3))) void*)l, 16, 0, 0);
}

// Swizzle convention for [rows][32 k] fp16 LDS tiles (64 B rows, bank period
// = 2 rows): logical k-chunk q (8 elems) of row r lives at phys chunk
// q ^ ((r>>1)&3).  Staged via pre-swizzled global source (gload_lds dest
// stays linear), read back with the same XOR.

// ---------------------------------------------------------------------------
// Pass 1a (fused path): x -> Xh, Xl, Xt in one pass. 64x64 LDS transpose.
// ---------------------------------------------------------------------------
__global__ __launch_bounds__(256) void cast_transpose(
    const float* __restrict__ x, _Float16* __restrict__ Xh,
    _Float16* __restrict__ Xl, _Float16* __restrict__ Xt)
{
    __shared__ __attribute__((aligned(16))) _Float16 tile[64 * 66];
    const int b = blockIdx.z, c0 = blockIdx.y * 64, n0 = blockIdx.x * 64;
    const int t = threadIdx.x;
    const int lr = t >> 4;          // 0..15
    const int lc = (t & 15) * 4;    // 0,4,...,60
    const size_t xbase = (size_t)b * NC * NN;

#pragma unroll
    for (int p = 0; p < 4; ++p) {
        const int r = p * 16 + lr;
        const size_t off = xbase + (size_t)(c0 + r) * NN + (n0 + lc);
        const float4 v = *(const float4*)(x + off);
        const _Float16 h0 = (_Float16)v.x, h1 = (_Float16)v.y;
        const _Float16 h2 = (_Float16)v.z, h3 = (_Float16)v.w;
        h4_t hv = {h0, h1, h2, h3};
        *(h4_t*)(Xh + off) = hv;
        h4_t lv = {(_Float16)(v.x - (float)h0), (_Float16)(v.y - (float)h1),
                   (_Float16)(v.z - (float)h2), (_Float16)(v.w - (float)h3)};
        *(h4_t*)(Xl + off) = lv;
        tile[r * 66 + lc + 0] = h0;
        tile[r * 66 + lc + 1] = h1;
        tile[r * 66 + lc + 2] = h2;
        tile[r * 66 + lc + 3] = h3;
    }
    __syncthreads();
    const size_t tbase = (size_t)b * NN * NC;
#pragma unroll
    for (int p = 0; p < 4; ++p) {
        const int rn = p * 16 + lr;
        h4_t w;
        w[0] = tile[(lc + 0) * 66 + rn];
        w[1] = tile[(lc + 1) * 66 + rn];
        w[2] = tile[(lc + 2) * 66 + rn];
        w[3] = tile[(lc + 3) * 66 + rn];
        *(h4_t*)(Xt + tbase + (size_t)(n0 + rn) * NC + (c0 + lc)) = w;
    }
}

// ---------------------------------------------------------------------------
// Pass 1b (fallback): x -> Xh, Xl only.
// ---------------------------------------------------------------------------
__global__ __launch_bounds__(256) void cast_hl(
    const float* __restrict__ x, _Float16* __restrict__ Xh,
    _Float16* __restrict__ Xl)
{
    const size_t total = (size_t)NB * NC * NN / 4;
    for (size_t i = (size_t)blockIdx.x * 256 + threadIdx.x; i < total;
         i += (size_t)gridDim.x * 256) {
        const float4 v = ((const float4*)x)[i];
        const _Float16 h0 = (_Float16)v.x, h1 = (_Float16)v.y;
        const _Float16 h2 = (_Float16)v.z, h3 = (_Float16)v.w;
        h4_t hv = {h0, h1, h2, h3};
        h4_t lv = {(_Float16)(v.x - (float)h0), (_Float16)(v.y - (float)h1),
                   (_Float16)(v.z - (float)h2), (_Float16)(v.w - (float)h3)};
        ((h4_t*)Xh)[i] = hv;
        ((h4_t*)Xl)[i] = lv;
    }
}

// ---------------------------------------------------------------------------
// Pass 2: partial energy, symmetric lower-tri tiles, split-K. m97 structure
// (frozen this round). Read swizzle: chunk ^= (row>>1)&3.
// ---------------------------------------------------------------------------
__global__ __launch_bounds__(256, 4) void gemm1_energy(
    const _Float16* __restrict__ Xh, const _Float16* __restrict__ Xl,
    float* __restrict__ part)
{
    __shared__ __attribute__((aligned(16))) _Float16 sAh[128 * 32];
    __shared__ __attribute__((aligned(16))) _Float16 sBh[128 * 32];
    __shared__ __attribute__((aligned(16))) _Float16 sAl[128 * 32];
    __shared__ __attribute__((aligned(16))) _Float16 sBl[128 * 32];

    const int flat = blockIdx.x;          // 0..1279
    const int xcd  = flat & 7;
    const int slot = flat >> 3;           // 0..159
    const int grp  = xcd + 8 * (slot / 10);   // 0..127 (bijective)
    const int mem  = slot % 10;           // 0..9 lower-tri tile index
    const int b    = grp >> 2;
    const int s    = grp & (NSPLIT - 1);

    const int ti = (int)((sqrtf(8.0f * (float)mem + 1.0f) - 1.0f) * 0.5f);
    const int tj = mem - ((ti * (ti + 1)) >> 1);
    const bool diag = (ti == tj);

    const int t = threadIdx.x;
    const int wave = t >> 6, lane = t & 63;
    const int srow = t >> 2;
    // pre-swizzled staging source: logical chunk = phys ^ ((row>>1)&3)
    const int scol = (((t & 3) ^ ((t >> 3) & 3)) * 8);

    const size_t xb = (size_t)b * NC * NN + (size_t)s * KCH;
    const _Float16* gAh = Xh + xb + (size_t)(ti * 128 + srow) * NN + scol;
    const _Float16* gBh = Xh + xb + (size_t)(tj * 128 + srow) * NN + scol;
    const _Float16* gAl = Xl + xb + (size_t)(ti * 128 + srow) * NN + scol;
    const _Float16* gBl = Xl + xb + (size_t)(tj * 128 + srow) * NN + scol;

    const int wr = wave >> 1, wc = wave & 1;
    const int fr = lane & 15, fko = (lane >> 4) * 8;
    const int hi4 = (lane >> 4) * 4;
    const int fsw = fko ^ (((fr >> 1) & 3) << 3);   // read swizzle

    const _Float16* rBh = diag ? sAh : sBh;
    const _Float16* rBl = diag ? sAl : sBl;

    f4_t acc[4][4];
#pragma unroll
    for (int m = 0; m < 4; ++m)
#pragma unroll
        for (int n = 0; n < 4; ++n) acc[m][n] = (f4_t){0.f, 0.f, 0.f, 0.f};

    for (int k0 = 0; k0 < KCH; k0 += 32) {
        gload16(gAh + k0,                   sAh + wave * 512);
        gload16(gAh + k0 + 64 * (size_t)NN, sAh + 2048 + wave * 512);
        gload16(gAl + k0,                   sAl + wave * 512);
        gload16(gAl + k0 + 64 * (size_t)NN, sAl + 2048 + wave * 512);
        if (!diag) {
            gload16(gBh + k0,                   sBh + wave * 512);
            gload16(gBh + k0 + 64 * (size_t)NN, sBh + 2048 + wave * 512);
            gload16(gBl + k0,                   sBl + wave * 512);
            gload16(gBl + k0 + 64 * (size_t)NN, sBl + 2048 + wave * 512);
        }
        __syncthreads();

        h8_t ah[4], bh[4], al[4], bl[4];
#pragma unroll
        for (int m = 0; m < 4; ++m) {
            ah[m] = *(const h8_t*)(sAh + (wr * 64 + m * 16 + fr) * 32 + fsw);
            bh[m] = *(const h8_t*)(rBh + (wc * 64 + m * 16 + fr) * 32 + fsw);
            al[m] = *(const h8_t*)(sAl + (wr * 64 + m * 16 + fr) * 32 + fsw);
            bl[m] = *(const h8_t*)(rBl + (wc * 64 + m * 16 + fr) * 32 + fsw);
        }
#pragma unroll
        for (int m = 0; m < 4; ++m)
#pragma unroll
            for (int nf = 0; nf < 4; ++nf) {
                acc[nf][m] = __builtin_amdgcn_mfma_f32_16x16x32_f16(bh[nf], ah[m], acc[nf][m], 0, 0, 0);
                acc[nf][m] = __builtin_amdgcn_mfma_f32_16x16x32_f16(bl[nf], ah[m], acc[nf][m], 0, 0, 0);
                acc[nf][m] = __builtin_amdgcn_mfma_f32_16x16x32_f16(bh[nf], al[m], acc[nf][m], 0, 0, 0);
            }
        __syncthreads();
    }

    float* pb = part + ((size_t)s * NB + b) * (NC * NC);
#pragma unroll
    for (int m = 0; m < 4; ++m) {
        const int i = ti * 128 + wr * 64 + m * 16 + fr;
#pragma unroll
        for (int nf = 0; nf < 4; ++nf) {
            const int jjb = tj * 128 + wc * 64 + nf * 16 + hi4;
            *(f4_t*)(pb + (size_t)i * NC + jjb) = acc[nf][m];
            if (!diag) {
#pragma unroll
                for (int j = 0; j < 4; ++j)
                    pb[(size_t)(jjb + j) * NC + i] = acc[nf][m][j];
            }
        }
    }
}

// ---------------------------------------------------------------------------
// Pass 3: attn = softmax(min(e) - e), e = sum of NSPLIT partials. 1 wave/row.
// ---------------------------------------------------------------------------
__global__ __launch_bounds__(256) void softmax_inv(
    const float* __restrict__ part, _Float16* __restrict__ attn)
{
    const int row = blockIdx.x * 4 + (threadIdx.x >> 6);
    const int lane = threadIdx.x & 63;
    const size_t roff = (size_t)row * NC;

    float4 a0 = {0.f, 0.f, 0.f, 0.f}, a1 = {0.f, 0.f, 0.f, 0.f};
#pragma unroll
    for (int s = 0; s < NSPLIT; ++s) {
        const float4* p = (const float4*)(part + (size_t)s * NB * NC * NC + roff);
        const float4 v0 = p[lane], v1 = p[64 + lane];
        a0.x += v0.x; a0.y += v0.y; a0.z += v0.z; a0.w += v0.w;
        a1.x += v1.x; a1.y += v1.y; a1.z += v1.z; a1.w += v1.w;
    }

    float mn = fminf(fminf(fminf(a0.x, a0.y), fminf(a0.z, a0.w)),
                     fminf(fminf(a1.x, a1.y), fminf(a1.z, a1.w)));
#pragma unroll
    for (int off = 32; off; off >>= 1) mn = fminf(mn, __shfl_xor(mn, off));

    const float w0 = __expf(mn - a0.x), w1 = __expf(mn - a0.y);
    const float w2 = __expf(mn - a0.z), w3 = __expf(mn - a0.w);
    const float w4 = __expf(mn - a1.x), w5 = __expf(mn - a1.y);
    const float w6 = __expf(mn - a1.z), w7 = __expf(mn - a1.w);
    float sum = ((w0 + w1) + (w2 + w3)) + ((w4 + w5) + (w6 + w7));
#pragma unroll
    for (int off = 32; off; off >>= 1) sum += __shfl_xor(sum, off);
    const float inv = 1.0f / sum;

    h4_t o0 = {(_Float16)(w0 * inv), (_Float16)(w1 * inv),
               (_Float16)(w2 * inv), (_Float16)(w3 * inv)};
    h4_t o1 = {(_Float16)(w4 * inv), (_Float16)(w5 * inv),
               (_Float16)(w6 * inv), (_Float16)(w7 * inv)};
    ((h4_t*)(attn + roff))[lane] = o0;
    ((h4_t*)(attn + roff))[64 + lane] = o1;
}

// ---------------------------------------------------------------------------
// Pass 4 (fallback only): Xt = Xh^T per batch.
// ---------------------------------------------------------------------------
__global__ __launch_bounds__(256) void transpose_h(
    const _Float16* __restrict__ Xh, _Float16* __restrict__ Xt)
{
    __shared__ __attribute__((aligned(16))) _Float16 tile[64 * 66];
    const int b = blockIdx.z, c0 = blockIdx.y * 64, n0 = blockIdx.x * 64;
    const int t = threadIdx.x;
    const int lr = t >> 4;
    const int lc = (t & 15) * 4;
    const size_t hbase = (size_t)b * NC * NN;

#pragma unroll
    for (int p = 0; p < 4; ++p) {
        const int r = p * 16 + lr;
        const h4_t v = *(const h4_t*)(Xh + hbase + (size_t)(c0 + r) * NN + (n0 + lc));
        tile[r * 66 + lc + 0] = v[0];
        tile[r * 66 + lc + 1] = v[1];
        tile[r * 66 + lc + 2] = v[2];
        tile[r * 66 + lc + 3] = v[3];
    }
    __syncthreads();
    const size_t tbase = (size_t)b * NN * NC;
#pragma unroll
    for (int p = 0; p < 4; ++p) {
        const int rn = p * 16 + lr;
        h4_t w;
        w[0] = tile[(lc + 0) * 66 + rn];
        w[1] = tile[(lc + 1) * 66 + rn];
        w[2] = tile[(lc + 2) * 66 + rn];
        w[3] = tile[(lc + 3) * 66 + rn];
        *(h4_t*)(Xt + tbase + (size_t)(n0 + rn) * NC + (c0 + lc)) = w;
    }
}

// ---------------------------------------------------------------------------
// Pass 5: out = gamma * (attn @ x) + x.
// 3-buffer LDS pipeline, 2-deep prefetch, counted vmcnt(4), ONE barrier/iter.
// All operands staged via gload_lds (pure vmcnt queue: exactly 4 loads/tile).
// Buffer rotation: tile t lives in buf[t%3]; STAGE(t+2) issued in iter t
// AFTER the barrier (so every wave is past iter t-1's reads of buf[(t+2)%3]).
// ---------------------------------------------------------------------------
__global__ __launch_bounds__(256) void gemm2_out(
    const _Float16* __restrict__ attn, const _Float16* __restrict__ Xt,
    const _Float16* __restrict__ Xh, const float* __restrict__ gammap,
    float* __restrict__ out)
{
    __shared__ __attribute__((aligned(16))) _Float16 sA[3][128 * 32];
    __shared__ __attribute__((aligned(16))) _Float16 sB[3][128 * 32];

    const int flat = blockIdx.x;            // 0..4095
    const int xcd  = flat & 7;
    const int slot = flat >> 3;              // 0..511
    const int b    = xcd + 8 * (slot >> 7);  // batch pinned to XCD
    const int memb = slot & 127;
    const int brow = (memb & 3) * 128;       // c tile (4)
    const int bcol = (memb >> 2) * 128;      // n tile (32)

    const int t = threadIdx.x;
    const int wave = t >> 6, lane = t & 63;
    const int wr = wave >> 1, wc = wave & 1;
    const int fr = lane & 15, fq = lane >> 4;
    const int hi4 = fq * 4;

    // staging geometry: 2 passes of 64 rows; row rr = t>>2, phys chunk t&3;
    // pre-swizzled source chunk = (t&3) ^ ((rr>>1)&3)
    const int rr = t >> 2;
    const int sck = (((t & 3) ^ ((rr >> 1) & 3)) * 8);
    const _Float16* gA = attn + (size_t)b * NC * NC + (size_t)brow * NC;
    const _Float16* gB = Xt   + (size_t)b * NN * NC + (size_t)bcol * NC;

    f4_t acc[4][4];
#pragma unroll
    for (int m = 0; m < 4; ++m)
#pragma unroll
        for (int n = 0; n < 4; ++n) acc[m][n] = (f4_t){0.f, 0.f, 0.f, 0.f};

#define STG2(buf, k0)                                                         \
    {                                                                         \
        gload16(gA + (size_t)rr * NC + (k0) + sck,        &sA[buf][0] + t * 8); \
        gload16(gA + (size_t)(64 + rr) * NC + (k0) + sck, &sA[buf][0] + 2048 + t * 8); \
        gload16(gB + (size_t)rr * NC + (k0) + sck,        &sB[buf][0] + t * 8); \
        gload16(gB + (size_t)(64 + rr) * NC + (k0) + sck, &sB[buf][0] + 2048 + t * 8); \
    }

    STG2(0, 0);
    STG2(1, 32);

#pragma unroll
    for (int it = 0; it < 16; ++it) {
        if (it < 15) {
            asm volatile("s_waitcnt vmcnt(4)" ::: "memory");
        } else {
            asm volatile("s_waitcnt vmcnt(0)" ::: "memory");
        }
        __builtin_amdgcn_s_barrier();
        if (it + 2 < 16) STG2((it + 2) % 3, (it + 2) * 32);

        const _Float16* cA = &sA[it % 3][0];
        const _Float16* cB = &sB[it % 3][0];
        h8_t a_[4], b_[4];
#pragma unroll
        for (int m = 0; m < 4; ++m) {
            const int ar = wr * 64 + m * 16 + fr;
            const int br = wc * 64 + m * 16 + fr;
            a_[m] = *(const h8_t*)(cA + ar * 32 + ((fq ^ ((ar >> 1) & 3)) * 8));
            b_[m] = *(const h8_t*)(cB + br * 32 + ((fq ^ ((br >> 1) & 3)) * 8));
        }
#pragma unroll
        for (int m = 0; m < 4; ++m)
#pragma unroll
            for (int nf = 0; nf < 4; ++nf)
                acc[nf][m] = __builtin_amdgcn_mfma_f32_16x16x32_f16(
                    b_[nf], a_[m], acc[nf][m], 0, 0, 0);
    }
#undef STG2

    const float g = gammap[0];
    const _Float16* xb = Xh + (size_t)b * NC * NN;
    float* ob = out + (size_t)b * NC * NN;
#pragma unroll
    for (int m = 0; m < 4; ++m) {
        const int c_ = brow + wr * 64 + m * 16 + fr;
#pragma unroll
        for (int nf = 0; nf < 4; ++nf) {
            const int n_ = bcol + wc * 64 + nf * 16 + hi4;
            const size_t off = (size_t)c_ * NN + n_;
            const h4_t xv = *(const h4_t*)(xb + off);
            f4_t o;
#pragma unroll
            for (int j = 0; j < 4; ++j)
                o[j] = g * acc[nf][m][j] + (float)xv[j];
            *(f4_t*)(ob + off) = o;
        }
    }
}

// ---------------------------------------------------------------------------
extern "C" void kernel_launch(void* const* d_in, const int* in_sizes, int n_in,
                              void* d_out, int out_size, void* d_ws, size_t ws_size,
                              hipStream_t stream)
{
    const float* x     = (const float*)d_in[0];
    const float* gamma = (const float*)d_in[1];
    float* out = (float*)d_out;
    char* ws = (char*)d_ws;

    if (ws_size >= 553648128ull) {
        // Fused path: Xh | Xl | Xt | attn | part
        _Float16* Xh   = (_Float16*)(ws);
        _Float16* Xl   = (_Float16*)(ws + 134217728ull);
        _Float16* Xt   = (_Float16*)(ws + 268435456ull);
        _Float16* attn = (_Float16*)(ws + 402653184ull);
        float*    part = (float*)   (ws + 419430400ull);

        cast_transpose<<<dim3(NN / 64, NC / 64, NB), 256, 0, stream>>>(x, Xh, Xl, Xt);
        gemm1_energy<<<dim3(10 * NSPLIT * NB), 256, 0, stream>>>(Xh, Xl, part);
        softmax_inv<<<dim3(NB * NC / 4), 256, 0, stream>>>(part, attn);
        gemm2_out<<<dim3(4096), 256, 0, stream>>>(attn, Xt, Xh, gamma, out);
    } else {
        // Fallback: Xh | Xl/Xt (time-shared) | attn | part
        _Float16* Xh   = (_Float16*)(ws);
        _Float16* XlXt = (_Float16*)(ws + 134217728ull);
        _Float16* attn = (_Float16*)(ws + 268435456ull);
        float*    part = (float*)   (ws + 285212672ull);

        cast_hl<<<dim3(2048), 256, 0, stream>>>(x, Xh, XlXt);
        gemm1_energy<<<dim3(10 * NSPLIT * NB), 256, 0, stream>>>(Xh, XlXt, part);
        softmax_inv<<<dim3(NB * NC / 4), 256, 0, stream>>>(part, attn);
        transpose_h<<<dim3(NN / 64, NC / 64, NB), 256, 0, stream>>>(Xh, XlXt);
        gemm2_out<<<dim3(4096), 256, 0, stream>>>(attn, XlXt, Xh, gamma, out);
    }
}